// Round 5
// baseline (116.240 us; speedup 1.0000x reference)
//
#include <hip/hip_runtime.h>
#include <hip/hip_bf16.h>

#define L_N 64
#define T_N 8192
#define K_N 128
#define N_N 128
#define BM  128
#define NT  8      // tiles per persistent block

typedef __attribute__((ext_vector_type(8))) short short8;   // 8 bf16 = 4 VGPR
typedef __attribute__((ext_vector_type(4))) float f32x4;    // MFMA acc

__device__ __forceinline__ unsigned short f2bf(float f) {
    union { float f; unsigned u; } c; c.f = f;
    return (unsigned short)((c.u + 0x7fffu + ((c.u >> 16) & 1u)) >> 16);  // RNE
}

// Prepass: w [L][K][N] fp32 -> pre-fragmented bf16  wf[l][ni][kk][lane][j]
//   element (l,ni,kk,lane,j) = w[l][ kk*32 + (lane>>4)*8 + j ][ ni*16 + (lane&15) ]
// (verified R2-R4). Main kernel stages wf[l] to LDS as a LINEAR copy; fragment
// reads are lane-consecutive 16B -> conflict-free by construction.
__global__ __launch_bounds__(256) void wfrag_kernel(const float* __restrict__ w,
                                                    unsigned short* __restrict__ wf) {
    __shared__ float lds[K_N * 129];            // +1 pad, 66 KB
    const int l = blockIdx.x;
    const float* wl = w + (size_t)l * (K_N * N_N);
    const int tid = threadIdx.x;
    #pragma unroll
    for (int i = 0; i < 16; ++i) {
        int f = i * 256 + tid;                  // float4 idx, coalesced
        float4 v = ((const float4*)wl)[f];
        int k = f >> 5, n = (f & 31) * 4;
        lds[k * 129 + n + 0] = v.x;
        lds[k * 129 + n + 1] = v.y;
        lds[k * 129 + n + 2] = v.z;
        lds[k * 129 + n + 3] = v.w;
    }
    __syncthreads();
    unsigned short* o = wf + (size_t)l * (N_N * K_N);
    #pragma unroll
    for (int c = 0; c < 16; ++c) {
        int chunk = c * 256 + tid;              // ushort4 idx, coalesced write
        int j0   = (chunk & 1) * 4;
        int lane = (chunk >> 1) & 63;
        int kk   = (chunk >> 7) & 3;
        int ni   = chunk >> 9;
        int n  = ni * 16 + (lane & 15);
        int kb = kk * 32 + (lane >> 4) * 8 + j0;
        ushort4 ov;
        ov.x = f2bf(lds[(kb + 0) * 129 + n]);
        ov.y = f2bf(lds[(kb + 1) * 129 + n]);
        ov.z = f2bf(lds[(kb + 2) * 129 + n]);
        ov.w = f2bf(lds[(kb + 3) * 129 + n]);
        ((ushort4*)o)[chunk] = ov;
    }
}

// Main: persistent block = 8 tiles of one layer. w in LDS once; per tile:
//   barrier / convert reg-prefetched x -> swizzled LDS / barrier /
//   issue next tile's x loads (overlap MFMA+epilogue+stores) / MFMA /
//   barrier-free per-wave epilogue (own 4KB LDS window, 2 col-halves).
__global__ __launch_bounds__(512, 4) void gl_kernel(const float* __restrict__ x,
                                                    const unsigned short* __restrict__ wf,
                                                    const float* __restrict__ bias,
                                                    float* __restrict__ out) {
    __shared__ __align__(16) char smem[65536];
    unsigned short* xs  = (unsigned short*)smem;            // 32KB x bf16 (swizzled) + epilogue windows
    unsigned short* wsh = (unsigned short*)(smem + 32768);  // 32KB w fragments, persistent

    const int tid  = threadIdx.x;
    const int lane = tid & 63;
    const int wid  = tid >> 6;                  // 8 waves; wave owns rows [wid*16, wid*16+16)
    const int lr   = lane & 15;
    const int lg   = lane >> 4;

    const int bid = blockIdx.x;                 // 512 blocks = 64 layers x 8 sub-blocks
    const int l   = bid >> 3;
    const int sub = bid & 7;

    // stage w once (linear 32KB copy, conflict-free both sides)
    const unsigned short* wl = wf + (size_t)l * (N_N * K_N);
    #pragma unroll
    for (int i = 0; i < 4; ++i) {
        int c = i * 512 + tid;
        ((short8*)wsh)[c] = ((const short8*)wl)[c];
    }

    const float* bl  = bias + l * N_N;
    const float* xg0 = x + ((size_t)l * T_N + (size_t)sub * (NT * BM)) * K_N;

    // prologue: prefetch tile 0 into registers (32 VGPR)
    float4 pf[8];                               // static indices only (rule #20)
    #pragma unroll
    for (int j = 0; j < 8; ++j)
        pf[j] = ((const float4*)xg0)[j * 512 + tid];

    for (int it = 0; it < NT; ++it) {
        __syncthreads();                        // prev epilogue LDS reads done (it=0: w-stage)
        // convert pf -> xs (swizzled 8B writes; R1/R4-verified, 0 conflicts)
        #pragma unroll
        for (int j = 0; j < 8; ++j) {
            int f = j * 512 + tid;              // float4 index within tile
            int row = f >> 5;
            int kc  = (f & 31) * 4;
            union { unsigned short s[4]; unsigned long long u; } p;
            p.s[0] = f2bf(pf[j].x); p.s[1] = f2bf(pf[j].y);
            p.s[2] = f2bf(pf[j].z); p.s[3] = f2bf(pf[j].w);
            int us = (row * K_N + kc) ^ ((row & 7) << 3);
            *(unsigned long long*)&xs[us] = p.u;
        }
        __syncthreads();                        // staging visible to all waves

        // issue next tile's loads now: latency hides under MFMA + epilogue + stores
        if (it + 1 < NT) {
            const float4* nx = (const float4*)(xg0 + (size_t)(it + 1) * BM * K_N);
            #pragma unroll
            for (int j = 0; j < 8; ++j)
                pf[j] = nx[j * 512 + tid];
        }

        // MFMA: wave computes its 16 rows x 128 cols
        f32x4 acc[8];
        #pragma unroll
        for (int ni = 0; ni < 8; ++ni)
            acc[ni] = (f32x4){0.f, 0.f, 0.f, 0.f};
        const int row = wid * 16 + lr;
        #pragma unroll
        for (int kk = 0; kk < 4; ++kk) {
            const short8 xb = *(const short8*)&xs[(row * K_N + kk * 32 + lg * 8) ^ ((row & 7) << 3)];
            #pragma unroll
            for (int ni = 0; ni < 8; ++ni) {
                const short8 wv = ((const short8*)wsh)[(ni * 4 + kk) * 64 + lane];
                acc[ni] = __builtin_amdgcn_mfma_f32_16x16x32_bf16(wv, xb, acc[ni], 0, 0, 0);
            }
        }

        // barrier-free epilogue: wave-private 4KB window = its OWN 16 x-rows
        // (only this wave reads them, and its xb reads are complete by now)
        float4* osm = ((float4*)smem) + wid * 256;   // 256 f4 = 4KB
        float4* og4 = (float4*)(out + ((size_t)l * T_N + (size_t)(sub * NT + it) * BM) * N_N);
        #pragma unroll
        for (int h = 0; h < 2; ++h) {           // column halves [h*64, h*64+64)
            #pragma unroll
            for (int q = 0; q < 4; ++q) {
                const int ni = h * 4 + q;
                const float4 bv = *(const float4*)(bl + ni * 16 + lg * 4);
                float4 r;
                r.x = acc[ni][0] + bv.x;
                r.y = acc[ni][1] + bv.y;
                r.z = acc[ni][2] + bv.z;
                r.w = acc[ni][3] + bv.w;
                osm[lr * 16 + ((q * 4 + lg) ^ lr)] = r;   // XOR-swizzled, row=lr
            }
            #pragma unroll
            for (int q2 = 0; q2 < 4; ++q2) {    // flat read -> 256B-contiguous stores
                const int fi = q2 * 64 + lane;
                const int rr = fi >> 4, cc = fi & 15;
                const float4 v = osm[rr * 16 + (cc ^ rr)];
                og4[(size_t)(wid * 16 + rr) * 32 + h * 16 + cc] = v;
            }
        }
    }
}

extern "C" void kernel_launch(void* const* d_in, const int* in_sizes, int n_in,
                              void* d_out, int out_size, void* d_ws, size_t ws_size,
                              hipStream_t stream) {
    const float* x = (const float*)d_in[0];
    const float* w = (const float*)d_in[1];
    const float* b = (const float*)d_in[2];
    float* out = (float*)d_out;
    unsigned short* wf = (unsigned short*)d_ws;   // 2 MB scratch, rewritten every call

    wfrag_kernel<<<L_N, 256, 0, stream>>>(w, wf);
    gl_kernel<<<L_N * (T_N / BM) / NT, 512, 0, stream>>>(x, wf, b, out);
}

// Round 6
// 110.768 us; speedup vs baseline: 1.0494x; 1.0494x over previous
//
#include <hip/hip_runtime.h>
#include <hip/hip_bf16.h>

#define L_N 64
#define T_N 8192
#define K_N 128
#define N_N 128
#define BM  128
#define NT  2      // tiles per block: keeps 2048 blocks (scheduling slack) + 1 prefetch overlap

typedef __attribute__((ext_vector_type(8))) short short8;   // 8 bf16 = 4 VGPR
typedef __attribute__((ext_vector_type(4))) float f32x4;    // MFMA acc

__device__ __forceinline__ unsigned short f2bf(float f) {
    union { float f; unsigned u; } c; c.f = f;
    return (unsigned short)((c.u + 0x7fffu + ((c.u >> 16) & 1u)) >> 16);  // RNE
}

// Prepass: w [L][K][N] fp32 -> pre-fragmented bf16  wf[l][ni][kk][lane][j]
//   element (l,ni,kk,lane,j) = w[l][ kk*32 + (lane>>4)*8 + j ][ ni*16 + (lane&15) ]
// (verified R2-R5). Main kernel stages wf[l] to LDS as a LINEAR copy; fragment
// reads are lane-consecutive 16B -> conflict-free by construction.
__global__ __launch_bounds__(256) void wfrag_kernel(const float* __restrict__ w,
                                                    unsigned short* __restrict__ wf) {
    __shared__ float lds[K_N * 129];            // +1 pad, 66 KB
    const int l = blockIdx.x;
    const float* wl = w + (size_t)l * (K_N * N_N);
    const int tid = threadIdx.x;
    #pragma unroll
    for (int i = 0; i < 16; ++i) {
        int f = i * 256 + tid;                  // float4 idx, coalesced
        float4 v = ((const float4*)wl)[f];
        int k = f >> 5, n = (f & 31) * 4;
        lds[k * 129 + n + 0] = v.x;
        lds[k * 129 + n + 1] = v.y;
        lds[k * 129 + n + 2] = v.z;
        lds[k * 129 + n + 3] = v.w;
    }
    __syncthreads();
    unsigned short* o = wf + (size_t)l * (N_N * K_N);
    #pragma unroll
    for (int c = 0; c < 16; ++c) {
        int chunk = c * 256 + tid;              // ushort4 idx, coalesced write
        int j0   = (chunk & 1) * 4;
        int lane = (chunk >> 1) & 63;
        int kk   = (chunk >> 7) & 3;
        int ni   = chunk >> 9;
        int n  = ni * 16 + (lane & 15);
        int kb = kk * 32 + (lane >> 4) * 8 + j0;
        ushort4 ov;
        ov.x = f2bf(lds[(kb + 0) * 129 + n]);
        ov.y = f2bf(lds[(kb + 1) * 129 + n]);
        ov.z = f2bf(lds[(kb + 2) * 129 + n]);
        ov.w = f2bf(lds[(kb + 3) * 129 + n]);
        ((ushort4*)o)[chunk] = ov;
    }
}

// Main: block = 2 tiles of one layer (2048 blocks -> HW rebalancing slack kept).
// w staged to LDS once; tile 1's x loads issued before tile 0's MFMA so their
// HBM latency hides under compute+epilogue+stores. Wave-private barrier-free
// epilogue (2 barriers per tile total).
__global__ __launch_bounds__(512, 4) void gl_kernel(const float* __restrict__ x,
                                                    const unsigned short* __restrict__ wf,
                                                    const float* __restrict__ bias,
                                                    float* __restrict__ out) {
    __shared__ __align__(16) char smem[65536];
    unsigned short* xs  = (unsigned short*)smem;            // 32KB x bf16 (swizzled) + epilogue windows
    unsigned short* wsh = (unsigned short*)(smem + 32768);  // 32KB w fragments, persistent

    const int tid  = threadIdx.x;
    const int lane = tid & 63;
    const int wid  = tid >> 6;                  // 8 waves; wave owns rows [wid*16, wid*16+16)
    const int lr   = lane & 15;
    const int lg   = lane >> 4;

    const int bid = blockIdx.x;                 // 2048 blocks = 64 layers x 32 pairs
    const int l   = bid >> 5;
    const int sub = bid & 31;

    // stage w once (linear 32KB copy, conflict-free both sides)
    const unsigned short* wl = wf + (size_t)l * (N_N * K_N);
    #pragma unroll
    for (int i = 0; i < 4; ++i) {
        int c = i * 512 + tid;
        ((short8*)wsh)[c] = ((const short8*)wl)[c];
    }

    const float* bl  = bias + l * N_N;
    const float* xg0 = x + ((size_t)l * T_N + (size_t)sub * (NT * BM)) * K_N;

    // prologue: prefetch tile 0 into registers (32 VGPR)
    float4 pf[8];                               // static indices only (rule #20)
    #pragma unroll
    for (int j = 0; j < 8; ++j)
        pf[j] = ((const float4*)xg0)[j * 512 + tid];

    for (int it = 0; it < NT; ++it) {
        __syncthreads();                        // prev epilogue window reads done (it=0: w-stage)
        // convert pf -> xs (swizzled 8B writes; 0 conflicts, R1/R4-verified)
        #pragma unroll
        for (int j = 0; j < 8; ++j) {
            int f = j * 512 + tid;              // float4 index within tile
            int row = f >> 5;
            int kc  = (f & 31) * 4;
            union { unsigned short s[4]; unsigned long long u; } p;
            p.s[0] = f2bf(pf[j].x); p.s[1] = f2bf(pf[j].y);
            p.s[2] = f2bf(pf[j].z); p.s[3] = f2bf(pf[j].w);
            int us = (row * K_N + kc) ^ ((row & 7) << 3);
            *(unsigned long long*)&xs[us] = p.u;
        }
        __syncthreads();                        // staging visible to all waves

        // issue next tile's loads now: latency hides under MFMA + epilogue + stores
        if (it + 1 < NT) {
            const float4* nx = (const float4*)(xg0 + (size_t)(it + 1) * BM * K_N);
            #pragma unroll
            for (int j = 0; j < 8; ++j)
                pf[j] = nx[j * 512 + tid];
        }

        // MFMA: wave computes its 16 rows x 128 cols
        f32x4 acc[8];
        #pragma unroll
        for (int ni = 0; ni < 8; ++ni)
            acc[ni] = (f32x4){0.f, 0.f, 0.f, 0.f};
        const int row = wid * 16 + lr;
        #pragma unroll
        for (int kk = 0; kk < 4; ++kk) {
            const short8 xb = *(const short8*)&xs[(row * K_N + kk * 32 + lg * 8) ^ ((row & 7) << 3)];
            #pragma unroll
            for (int ni = 0; ni < 8; ++ni) {
                const short8 wv = ((const short8*)wsh)[(ni * 4 + kk) * 64 + lane];
                acc[ni] = __builtin_amdgcn_mfma_f32_16x16x32_bf16(wv, xb, acc[ni], 0, 0, 0);
            }
        }

        // barrier-free epilogue: wave-private 4KB window = its OWN 16 x-rows
        // (only this wave reads them, and its xb reads are complete by now)
        float4* osm = ((float4*)smem) + wid * 256;   // 256 f4 = 4KB
        float4* og4 = (float4*)(out + ((size_t)l * T_N + (size_t)(sub * NT + it) * BM) * N_N);
        #pragma unroll
        for (int h = 0; h < 2; ++h) {           // column halves [h*64, h*64+64)
            #pragma unroll
            for (int q = 0; q < 4; ++q) {
                const int ni = h * 4 + q;
                const float4 bv = *(const float4*)(bl + ni * 16 + lg * 4);
                float4 r;
                r.x = acc[ni][0] + bv.x;
                r.y = acc[ni][1] + bv.y;
                r.z = acc[ni][2] + bv.z;
                r.w = acc[ni][3] + bv.w;
                osm[lr * 16 + ((q * 4 + lg) ^ lr)] = r;   // XOR-swizzled, row=lr
            }
            #pragma unroll
            for (int q2 = 0; q2 < 4; ++q2) {    // flat read -> 256B-contiguous stores
                const int fi = q2 * 64 + lane;
                const int rr = fi >> 4, cc = fi & 15;
                const float4 v = osm[rr * 16 + (cc ^ rr)];
                og4[(size_t)(wid * 16 + rr) * 32 + h * 16 + cc] = v;
            }
        }
    }
}

extern "C" void kernel_launch(void* const* d_in, const int* in_sizes, int n_in,
                              void* d_out, int out_size, void* d_ws, size_t ws_size,
                              hipStream_t stream) {
    const float* x = (const float*)d_in[0];
    const float* w = (const float*)d_in[1];
    const float* b = (const float*)d_in[2];
    float* out = (float*)d_out;
    unsigned short* wf = (unsigned short*)d_ws;   // 2 MB scratch, rewritten every call

    wfrag_kernel<<<L_N, 256, 0, stream>>>(w, wf);
    gl_kernel<<<L_N * (T_N / BM) / NT, 512, 0, stream>>>(x, wf, b, out);
}